// Round 5
// baseline (518.317 us; speedup 1.0000x reference)
//
#include <hip/hip_runtime.h>
#include <stdint.h>

#define B_DIM 4096
#define DIN   2048
#define UNITS 2048
#define KDIM  4096   // DIN + UNITS
#define BK    64     // k per LDS tile
#define BM    256
#define BN    256    // 4 gates x 64 units

using s8v  = __attribute__((ext_vector_type(8))) short;    // 8 x bf16 (4 VGPRs)
using f16v = __attribute__((ext_vector_type(16))) float;   // 32x32 acc (16 f32)

__device__ __forceinline__ unsigned short f2bf(float f) {
    union { float f; unsigned u; } v; v.f = f;
    unsigned u = v.u;
    unsigned r = u + 0x7FFFu + ((u >> 16) & 1u);   // RNE
    return (unsigned short)(r >> 16);
}

__device__ __forceinline__ void gl2lds16(const unsigned short* g, unsigned short* l) {
    __builtin_amdgcn_global_load_lds(
        (const __attribute__((address_space(1))) unsigned int*)g,
        (__attribute__((address_space(3))) unsigned int*)l, 16, 0, 0);
}

// ---------------- fused pack: z = [x|h] -> bf16, W -> bf16 transposed ----------------
// blocks [0, 8192): pack_z. blocks [8192, 8192+2048): pack_w (64k x 256n per block).
#define NZ_BLOCKS 8192
#define NW_BLOCKS 2048
__global__ __launch_bounds__(256) void pack_all(
    const float* __restrict__ x, const float* __restrict__ h,
    const float* __restrict__ Wf, const float* __restrict__ Wi,
    const float* __restrict__ Wc, const float* __restrict__ Wo,
    unsigned short* __restrict__ zA, unsigned short* __restrict__ WB) {
    __shared__ unsigned short T[64][258];
    int t = threadIdx.x;
    int b = blockIdx.x;
    if (b < NZ_BLOCKS) {
        int ch  = b * 256 + t;              // 8-elem chunks, 512/row
        int m   = ch >> 9;
        int pos = (ch & 511) * 8;
        const float* src = (pos < DIN) ? (x + (size_t)m * DIN + pos)
                                       : (h + (size_t)m * UNITS + (pos - DIN));
        float4 v0 = *(const float4*)(src);
        float4 v1 = *(const float4*)(src + 4);
        s8v o;
        o[0]=f2bf(v0.x); o[1]=f2bf(v0.y); o[2]=f2bf(v0.z); o[3]=f2bf(v0.w);
        o[4]=f2bf(v1.x); o[5]=f2bf(v1.y); o[6]=f2bf(v1.z); o[7]=f2bf(v1.w);
        *(s8v*)(zA + (size_t)ch * 8) = o;
        return;
    }
    int bb  = b - NZ_BLOCKS;
    int g   = bb >> 9;            // 512 tiles per gate
    int rem = bb & 511;
    int kt  = rem & 63;           // 64 k-tiles
    int nt  = rem >> 6;           // 8 n-tiles
    const float* Wg = (g == 0) ? Wf : (g == 1) ? Wi : (g == 2) ? Wc : Wo;
    int k0 = kt * 64, n0 = nt * 256;
    const int wv = t >> 6, l = t & 63;
    #pragma unroll
    for (int i = 0; i < 16; ++i) {
        int r = i * 4 + wv;                  // one row per wave per iter
        int c = l * 4;
        float4 v = *(const float4*)(Wg + (size_t)(k0 + r) * UNITS + n0 + c);
        T[r][c+0] = f2bf(v.x); T[r][c+1] = f2bf(v.y);
        T[r][c+2] = f2bf(v.z); T[r][c+3] = f2bf(v.w);
    }
    __syncthreads();
    #pragma unroll
    for (int it = 0; it < 8; ++it) {
        int s  = it * 256 + t;
        int ul = s >> 3;                     // n-row 0..255
        int kl = (s & 7) * 8;                // k chunk
        s8v o;
        #pragma unroll
        for (int j = 0; j < 8; ++j) o[j] = (short)T[kl + j][ul];
        *(s8v*)(WB + (size_t)(g * UNITS + n0 + ul) * KDIM + k0 + kl) = o;
    }
}

// ---------------- 256^2-tile 8-wave phase-pipelined GEMM (32x32x16) + LSTM epilogue ----
// LDS per (buf,kh,matrix) region: 128 lines x 128 B; line L holds rows {2L,2L+1}.
// slog = (row&1)*4 + chunk; physical slot = slog ^ (L&7) -> conflict-free b128 reads
// (both 16-row and 32-row fragment patterns spread 8 lanes per slot position).
// Staging dest linear (global_load_lds); inverse swizzle on global source (both-sides).
// MFMA: 32x32x16 bf16 (2495 TF ubench vs 2075 for 16x16) — wave owns 4m x 2n tiles of
// 32x32; per phase: 8 MFMA, LGK0 restored (lgkmcnt(3) experiment regressed, round 4).
__global__ __launch_bounds__(512, 2) void lstm_gemm(
    const unsigned short* __restrict__ zA,   // 4096 x 4096 bf16
    const unsigned short* __restrict__ WB,   // 8192 x 4096 bf16, row n = g*2048+u
    const float* __restrict__ cin,
    const float* __restrict__ bfp, const float* __restrict__ bip,
    const float* __restrict__ bcp, const float* __restrict__ bop,
    float* __restrict__ out) {
    extern __shared__ unsigned short SMu[];   // 131072 B

    const int t    = threadIdx.x;
    const int lane = t & 63;
    const int wave = t >> 6;       // 0..7
    const int wm   = wave >> 2;    // 0..1  (m half)
    const int wn   = wave & 3;     // 0..3  (gate)
    const int l31  = lane & 31;
    const int kg   = lane >> 5;    // k-group within fragment

    // XCD-aware mapping: 2x4 super-grid of XCDs, each XCD owns 8 m-tiles x 8 u-tiles
    // (per-XCD panel set 32 MB; per-k-step L2 working set ~384 KB << 4 MB).
    int bid = blockIdx.x;
    int xcd = bid & 7, loc = bid >> 3;
    const int m0 = (((xcd & 1) << 3) | (loc & 7)) * BM;    // 16 m-tiles
    const int u0 = (((xcd >> 1) << 3) | (loc >> 3)) * 64;  // 32 u-tiles

    // ---- staging: slots s = t and t+512 per region; slot -> (line, phys slot) ----
    const int L    = t >> 3;
    const int p    = t & 7;
    const int slog = p ^ (L & 7);
    const int rr   = 2 * L + (slog >> 2);    // row 0..127
    const int ch   = slog & 3;               // 8-bf16 chunk within kh-half
    const unsigned short* gA0 = zA + (size_t)(m0 + rr) * KDIM + ch * 8;
    const unsigned short* gB0 = WB + (size_t)((rr >> 6) * UNITS + u0 + (rr & 63)) * KDIM + ch * 8;
    const int dst0 = t * 8;                  // ushort offsets, linear
    const int dst1 = (t + 512) * 8;

    // ---- fragment read offsets (ushorts) ----
    // row r = base32 + l31 (base32 mult of 32): line lh' = base32/2 + lh, lh = l31>>1,
    // phys slot = ((l31&1)*4 + ks*2 + kg) ^ (lh&7).  lo0/lo1 = ks 0/1 lane offsets.
    const int lh  = l31 >> 1;
    const int lo0 = lh * 64 + ((((lane & 1) << 2) | kg) ^ (lh & 7)) * 8;
    const int lo1 = lh * 64 + ((((lane & 1) << 2) | 2 | kg) ^ (lh & 7)) * 8;
    const int aoff = wm * 4096;              // + mtile*1024 + kh*8192 (+buf via cur)
    const int boff = 16384 + wn * 2048;      // + ntile*1024 + kh*8192

    f16v acc[4][2];
    #pragma unroll
    for (int i = 0; i < 4; ++i)
        #pragma unroll
        for (int j = 0; j < 2; ++j)
            #pragma unroll
            for (int r = 0; r < 16; ++r) acc[i][j][r] = 0.f;

#define STAGE_A(khv) do { \
    gl2lds16(gA0 + ko + (khv)*32, nxt + (khv)*8192 + dst0); \
    gl2lds16(gA0 + (size_t)128*KDIM + ko + (khv)*32, nxt + (khv)*8192 + dst1); } while(0)
#define STAGE_B(khv) do { \
    gl2lds16(gB0 + ko + (khv)*32, nxt + 16384 + (khv)*8192 + dst0); \
    gl2lds16(gB0 + (size_t)2*UNITS*KDIM + ko + (khv)*32, nxt + 16384 + (khv)*8192 + dst1); } while(0)
#define LDB4(khv) do { \
    const unsigned short* bp = cur + boff + (khv)*8192; \
    b[0][0] = *(const s8v*)(bp + lo0);        b[0][1] = *(const s8v*)(bp + lo1); \
    b[1][0] = *(const s8v*)(bp + 1024 + lo0); b[1][1] = *(const s8v*)(bp + 1024 + lo1); } while(0)
#define LDA4(khv, mpv) do { \
    const unsigned short* ap = cur + aoff + (khv)*8192 + (mpv)*2048; \
    a[0][0] = *(const s8v*)(ap + lo0);        a[0][1] = *(const s8v*)(ap + lo1); \
    a[1][0] = *(const s8v*)(ap + 1024 + lo0); a[1][1] = *(const s8v*)(ap + 1024 + lo1); } while(0)
#define MFMA8(mpv) do { \
    acc[(mpv)*2+0][0] = __builtin_amdgcn_mfma_f32_32x32x16_bf16(a[0][0], b[0][0], acc[(mpv)*2+0][0], 0,0,0); \
    acc[(mpv)*2+0][1] = __builtin_amdgcn_mfma_f32_32x32x16_bf16(a[0][0], b[1][0], acc[(mpv)*2+0][1], 0,0,0); \
    acc[(mpv)*2+1][0] = __builtin_amdgcn_mfma_f32_32x32x16_bf16(a[1][0], b[0][0], acc[(mpv)*2+1][0], 0,0,0); \
    acc[(mpv)*2+1][1] = __builtin_amdgcn_mfma_f32_32x32x16_bf16(a[1][0], b[1][0], acc[(mpv)*2+1][1], 0,0,0); \
    acc[(mpv)*2+0][0] = __builtin_amdgcn_mfma_f32_32x32x16_bf16(a[0][1], b[0][1], acc[(mpv)*2+0][0], 0,0,0); \
    acc[(mpv)*2+0][1] = __builtin_amdgcn_mfma_f32_32x32x16_bf16(a[0][1], b[1][1], acc[(mpv)*2+0][1], 0,0,0); \
    acc[(mpv)*2+1][0] = __builtin_amdgcn_mfma_f32_32x32x16_bf16(a[1][1], b[0][1], acc[(mpv)*2+1][0], 0,0,0); \
    acc[(mpv)*2+1][1] = __builtin_amdgcn_mfma_f32_32x32x16_bf16(a[1][1], b[1][1], acc[(mpv)*2+1][1], 0,0,0); } while(0)
#define BAR()  __builtin_amdgcn_s_barrier()
#define LGK0() do { asm volatile("s_waitcnt lgkmcnt(0)" ::: "memory"); \
                    __builtin_amdgcn_sched_barrier(0); } while(0)
#define VM(n)  asm volatile("s_waitcnt vmcnt(" #n ")" ::: "memory")

    // ---- prologue: stage tile 0 into buf 0 (issue order = consume order) ----
    {
        unsigned short* nxt = SMu;
        const int ko = 0;
        STAGE_A(0); STAGE_B(0);
        __builtin_amdgcn_sched_barrier(0);
        STAGE_A(1); STAGE_B(1);
        __builtin_amdgcn_sched_barrier(0);
    }
    VM(4);          // A_k0(0), B_k0(0) landed; k1 halves stay in flight
    BAR();

    s8v a[2][2], b[2][2];
    #pragma unroll 1
    for (int kt = 0; kt < 63; ++kt) {
        const unsigned short* cur = SMu + ((kt & 1) << 15);
        unsigned short* nxt = SMu + (((kt & 1) ^ 1) << 15);
        const int ko = (kt + 1) * BK;
        // phase 0: (kh0, mp0) | stage A_k0(t+1)
        LDB4(0); LDA4(0, 0); STAGE_A(0);
        BAR(); LGK0();
        __builtin_amdgcn_s_setprio(1); MFMA8(0); __builtin_amdgcn_s_setprio(0);
        BAR();
        // phase 1: (kh0, mp1) | stage B_k0(t+1) | vmcnt(4): k1(t) halves landed
        LDA4(0, 1); STAGE_B(0);
        BAR(); LGK0();
        __builtin_amdgcn_s_setprio(1); MFMA8(1); __builtin_amdgcn_s_setprio(0);
        VM(4);
        BAR();
        // phase 2: (kh1, mp0) | stage A_k1(t+1)
        LDB4(1); LDA4(1, 0); STAGE_A(1);
        BAR(); LGK0();
        __builtin_amdgcn_s_setprio(1); MFMA8(0); __builtin_amdgcn_s_setprio(0);
        BAR();
        // phase 3: (kh1, mp1) | stage B_k1(t+1) | vmcnt(4): k0(t+1) halves landed
        LDA4(1, 1); STAGE_B(1);
        BAR(); LGK0();
        __builtin_amdgcn_s_setprio(1); MFMA8(1); __builtin_amdgcn_s_setprio(0);
        VM(4);
        BAR();
    }
    // ---- tail: tile 63, no staging ----
    {
        const unsigned short* cur = SMu + ((63 & 1) << 15);
        LDB4(0); LDA4(0, 0);
        BAR(); LGK0();
        __builtin_amdgcn_s_setprio(1); MFMA8(0); __builtin_amdgcn_s_setprio(0);
        BAR();
        LDA4(0, 1);
        BAR(); LGK0();
        __builtin_amdgcn_s_setprio(1); MFMA8(1); __builtin_amdgcn_s_setprio(0);
        VM(0);
        BAR();
        LDB4(1); LDA4(1, 0);
        BAR(); LGK0();
        __builtin_amdgcn_s_setprio(1); MFMA8(0); __builtin_amdgcn_s_setprio(0);
        BAR();
        LDA4(1, 1);
        BAR(); LGK0();
        __builtin_amdgcn_s_setprio(1); MFMA8(1); __builtin_amdgcn_s_setprio(0);
        BAR();
    }

    // ---- fused epilogue: 4 chunks of 64 m-rows through padded f32 LDS ----
    // 32x32 C/D layout: col = lane&31, row = (reg&3) + 8*(reg>>2) + 4*(lane>>5).
    // All acc indices compile-time (rule #20).
    float* E = (float*)SMu;
    const int EW = 260;
    const int du = lane;
    float bF = bfp[u0 + du], bI = bip[u0 + du], bG = bcp[u0 + du], bO = bop[u0 + du];
    float* outh = out;
    float* outc = out + (size_t)B_DIM * UNITS;
    #pragma unroll
    for (int chk = 0; chk < 4; ++chk) {
        if (wm == (chk >> 1)) {
            #pragma unroll
            for (int mt = 0; mt < 2; ++mt)
                #pragma unroll
                for (int nt = 0; nt < 2; ++nt)
                    #pragma unroll
                    for (int reg = 0; reg < 16; ++reg) {
                        int rl  = mt * 32 + (reg & 3) + 8 * (reg >> 2) + 4 * kg;
                        int col = wn * 64 + nt * 32 + l31;
                        E[rl * EW + col] = acc[(chk & 1) * 2 + mt][nt][reg];
                    }
        }
        __syncthreads();
        #pragma unroll
        for (int v = 0; v < 8; ++v) {
            int rloc = v * 8 + wave;
            float F = E[rloc * EW +       du] + bF;
            float I = E[rloc * EW +  64 + du] + bI;
            float G = E[rloc * EW + 128 + du] + bG;
            float O = E[rloc * EW + 192 + du] + bO;
            int m = m0 + chk * 64 + rloc;
            size_t off = (size_t)m * UNITS + u0 + du;
            float cv = cin[off];
            float fg = 1.f / (1.f + __expf(-F));
            float ig = 1.f / (1.f + __expf(-I));
            float gg = 1.f - 2.f / (1.f + __expf(2.f * G));   // tanh, inf-safe
            float og = 1.f / (1.f + __expf(-O));
            float nc = fg * cv + ig * gg;
            float nh = og * (1.f - 2.f / (1.f + __expf(2.f * nc)));
            outc[off] = nc;
            outh[off] = nh;
        }
        __syncthreads();
    }
}

extern "C" void kernel_launch(void* const* d_in, const int* in_sizes, int n_in,
                              void* d_out, int out_size, void* d_ws, size_t ws_size,
                              hipStream_t stream) {
    const float* x  = (const float*)d_in[0];
    const float* h  = (const float*)d_in[1];
    const float* c  = (const float*)d_in[2];
    const float* Wf = (const float*)d_in[3];
    const float* bf = (const float*)d_in[4];
    const float* Wi = (const float*)d_in[5];
    const float* bi = (const float*)d_in[6];
    const float* Wc = (const float*)d_in[7];
    const float* bc = (const float*)d_in[8];
    const float* Wo = (const float*)d_in[9];
    const float* bo = (const float*)d_in[10];

    unsigned short* zA = (unsigned short*)d_ws;                 // 32 MB
    unsigned short* WB = zA + (size_t)B_DIM * KDIM;             // 64 MB

    hipFuncSetAttribute(reinterpret_cast<const void*>(lstm_gemm),
                        hipFuncAttributeMaxDynamicSharedMemorySize, 131072);

    pack_all<<<NZ_BLOCKS + NW_BLOCKS, 256, 0, stream>>>(x, h, Wf, Wi, Wc, Wo, zA, WB);
    lstm_gemm<<<dim3(512), 512, 131072, stream>>>(
        zA, WB, c, bf, bi, bc, bo, (float*)d_out);
}

// Round 6
// 516.503 us; speedup vs baseline: 1.0035x; 1.0035x over previous
//
#include <hip/hip_runtime.h>
#include <stdint.h>

#define B_DIM 4096
#define DIN   2048
#define UNITS 2048
#define KDIM  4096   // DIN + UNITS
#define BK    64     // k per LDS tile
#define BM    256
#define BN    256    // 4 gates x 64 units

using s8v  = __attribute__((ext_vector_type(8))) short;    // 8 x bf16 (4 VGPRs)
using f16v = __attribute__((ext_vector_type(16))) float;   // 32x32 acc (16 f32)

__device__ __forceinline__ unsigned short f2bf(float f) {
    union { float f; unsigned u; } v; v.f = f;
    unsigned u = v.u;
    unsigned r = u + 0x7FFFu + ((u >> 16) & 1u);   // RNE
    return (unsigned short)(r >> 16);
}

__device__ __forceinline__ void gl2lds16(const unsigned short* g, unsigned short* l) {
    __builtin_amdgcn_global_load_lds(
        (const __attribute__((address_space(1))) unsigned int*)g,
        (__attribute__((address_space(3))) unsigned int*)l, 16, 0, 0);
}

// ---------------- fused pack: z = [x|h] -> bf16, W -> bf16 transposed ----------------
// blocks [0, 8192): pack_z. blocks [8192, 8192+2048): pack_w (64k x 256n per block).
#define NZ_BLOCKS 8192
#define NW_BLOCKS 2048
__global__ __launch_bounds__(256) void pack_all(
    const float* __restrict__ x, const float* __restrict__ h,
    const float* __restrict__ Wf, const float* __restrict__ Wi,
    const float* __restrict__ Wc, const float* __restrict__ Wo,
    unsigned short* __restrict__ zA, unsigned short* __restrict__ WB) {
    __shared__ unsigned short T[64][258];
    int t = threadIdx.x;
    int b = blockIdx.x;
    if (b < NZ_BLOCKS) {
        int ch  = b * 256 + t;              // 8-elem chunks, 512/row
        int m   = ch >> 9;
        int pos = (ch & 511) * 8;
        const float* src = (pos < DIN) ? (x + (size_t)m * DIN + pos)
                                       : (h + (size_t)m * UNITS + (pos - DIN));
        float4 v0 = *(const float4*)(src);
        float4 v1 = *(const float4*)(src + 4);
        s8v o;
        o[0]=f2bf(v0.x); o[1]=f2bf(v0.y); o[2]=f2bf(v0.z); o[3]=f2bf(v0.w);
        o[4]=f2bf(v1.x); o[5]=f2bf(v1.y); o[6]=f2bf(v1.z); o[7]=f2bf(v1.w);
        *(s8v*)(zA + (size_t)ch * 8) = o;
        return;
    }
    int bb  = b - NZ_BLOCKS;
    int g   = bb >> 9;            // 512 tiles per gate
    int rem = bb & 511;
    int kt  = rem & 63;           // 64 k-tiles
    int nt  = rem >> 6;           // 8 n-tiles
    const float* Wg = (g == 0) ? Wf : (g == 1) ? Wi : (g == 2) ? Wc : Wo;
    int k0 = kt * 64, n0 = nt * 256;
    const int wv = t >> 6, l = t & 63;
    #pragma unroll
    for (int i = 0; i < 16; ++i) {
        int r = i * 4 + wv;                  // one row per wave per iter
        int c = l * 4;
        float4 v = *(const float4*)(Wg + (size_t)(k0 + r) * UNITS + n0 + c);
        T[r][c+0] = f2bf(v.x); T[r][c+1] = f2bf(v.y);
        T[r][c+2] = f2bf(v.z); T[r][c+3] = f2bf(v.w);
    }
    __syncthreads();
    #pragma unroll
    for (int it = 0; it < 8; ++it) {
        int s  = it * 256 + t;
        int ul = s >> 3;                     // n-row 0..255
        int kl = (s & 7) * 8;                // k chunk
        s8v o;
        #pragma unroll
        for (int j = 0; j < 8; ++j) o[j] = (short)T[kl + j][ul];
        *(s8v*)(WB + (size_t)(g * UNITS + n0 + ul) * KDIM + k0 + kl) = o;
    }
}

// ---------------- 256^2-tile 8-wave phase-pipelined GEMM (32x32x16) + LSTM epilogue ----
// LDS per (buf,kh,matrix) region: 128 lines x 128 B; line L holds rows {2L,2L+1}.
// Bank index = slot_phys*4 (+0..3): the 128B line offset vanishes mod 32 banks, so the
// swizzle must distinguish lanes l31 and l31+16 (whose lh differ only in bit 3).
// slog = (row&1)*4 + chunk; phys = slog ^ (L&7) ^ ((L>>3&1)<<1)  <-- bit-3 injection
// (round-5 lacked the last term -> quarter-wave pairs hit identical bank groups ->
//  25.17M conflicts). Now every vertical lane-quad {l,l+16,l+32,l+48} covers 4 distinct
// slots, same property as the verified conflict-free 16x16 layout.
// Staging dest linear (global_load_lds); inverse swizzle on global source (both-sides).
__global__ __launch_bounds__(512, 2) void lstm_gemm(
    const unsigned short* __restrict__ zA,   // 4096 x 4096 bf16
    const unsigned short* __restrict__ WB,   // 8192 x 4096 bf16, row n = g*2048+u
    const float* __restrict__ cin,
    const float* __restrict__ bfp, const float* __restrict__ bip,
    const float* __restrict__ bcp, const float* __restrict__ bop,
    float* __restrict__ out) {
    extern __shared__ unsigned short SMu[];   // 131072 B

    const int t    = threadIdx.x;
    const int lane = t & 63;
    const int wave = t >> 6;       // 0..7
    const int wm   = wave >> 2;    // 0..1  (m half)
    const int wn   = wave & 3;     // 0..3  (gate)
    const int l31  = lane & 31;
    const int kg   = lane >> 5;    // k-group within fragment

    // XCD-aware mapping: 2x4 super-grid of XCDs, each XCD owns 8 m-tiles x 8 u-tiles
    int bid = blockIdx.x;
    int xcd = bid & 7, loc = bid >> 3;
    const int m0 = (((xcd & 1) << 3) | (loc & 7)) * BM;    // 16 m-tiles
    const int u0 = (((xcd >> 1) << 3) | (loc >> 3)) * 64;  // 32 u-tiles

    // ---- staging: slots s = t and t+512 per region; slot -> (line, phys slot) ----
    // s+512 -> L+64: (L&7) and (L>>3)&1 both unchanged -> row +128, same chunk.
    const int L    = t >> 3;
    const int p    = t & 7;
    const int slog = (p ^ (L & 7)) ^ (((L >> 3) & 1) << 1);
    const int rr   = 2 * L + (slog >> 2);    // row 0..127
    const int ch   = slog & 3;               // 8-bf16 chunk within kh-half
    const unsigned short* gA0 = zA + (size_t)(m0 + rr) * KDIM + ch * 8;
    const unsigned short* gB0 = WB + (size_t)((rr >> 6) * UNITS + u0 + (rr & 63)) * KDIM + ch * 8;
    const int dst0 = t * 8;                  // ushort offsets, linear
    const int dst1 = (t + 512) * 8;

    // ---- fragment read offsets (ushorts) ----
    // row r = base32 + l31 (base32 mult of 32): line = base_lines + lh, lh = l31>>1;
    // base_lines mult of 16 -> line&7 = lh&7, (line>>3)&1 = (lh>>3)&1.
    const int lh  = l31 >> 1;
    const int lsw = (lh & 7) ^ (((lh >> 3) & 1) << 1);
    const int lo0 = lh * 64 + ((((l31 & 1) << 2) | kg) ^ lsw) * 8;       // ks=0
    const int lo1 = lh * 64 + ((((l31 & 1) << 2) | 2 | kg) ^ lsw) * 8;   // ks=1
    const int aoff = wm * 4096;              // + mtile*1024 + kh*8192 (+buf via cur)
    const int boff = 16384 + wn * 2048;      // + ntile*1024 + kh*8192

    f16v acc[4][2];
    #pragma unroll
    for (int i = 0; i < 4; ++i)
        #pragma unroll
        for (int j = 0; j < 2; ++j)
            #pragma unroll
            for (int r = 0; r < 16; ++r) acc[i][j][r] = 0.f;

#define STAGE_A(khv) do { \
    gl2lds16(gA0 + ko + (khv)*32, nxt + (khv)*8192 + dst0); \
    gl2lds16(gA0 + (size_t)128*KDIM + ko + (khv)*32, nxt + (khv)*8192 + dst1); } while(0)
#define STAGE_B(khv) do { \
    gl2lds16(gB0 + ko + (khv)*32, nxt + 16384 + (khv)*8192 + dst0); \
    gl2lds16(gB0 + (size_t)2*UNITS*KDIM + ko + (khv)*32, nxt + 16384 + (khv)*8192 + dst1); } while(0)
#define LDB4(khv) do { \
    const unsigned short* bp = cur + boff + (khv)*8192; \
    b[0][0] = *(const s8v*)(bp + lo0);        b[0][1] = *(const s8v*)(bp + lo1); \
    b[1][0] = *(const s8v*)(bp + 1024 + lo0); b[1][1] = *(const s8v*)(bp + 1024 + lo1); } while(0)
#define LDA4(khv, mpv) do { \
    const unsigned short* ap = cur + aoff + (khv)*8192 + (mpv)*2048; \
    a[0][0] = *(const s8v*)(ap + lo0);        a[0][1] = *(const s8v*)(ap + lo1); \
    a[1][0] = *(const s8v*)(ap + 1024 + lo0); a[1][1] = *(const s8v*)(ap + 1024 + lo1); } while(0)
#define MFMA8(mpv) do { \
    acc[(mpv)*2+0][0] = __builtin_amdgcn_mfma_f32_32x32x16_bf16(a[0][0], b[0][0], acc[(mpv)*2+0][0], 0,0,0); \
    acc[(mpv)*2+0][1] = __builtin_amdgcn_mfma_f32_32x32x16_bf16(a[0][0], b[1][0], acc[(mpv)*2+0][1], 0,0,0); \
    acc[(mpv)*2+1][0] = __builtin_amdgcn_mfma_f32_32x32x16_bf16(a[1][0], b[0][0], acc[(mpv)*2+1][0], 0,0,0); \
    acc[(mpv)*2+1][1] = __builtin_amdgcn_mfma_f32_32x32x16_bf16(a[1][0], b[1][0], acc[(mpv)*2+1][1], 0,0,0); \
    acc[(mpv)*2+0][0] = __builtin_amdgcn_mfma_f32_32x32x16_bf16(a[0][1], b[0][1], acc[(mpv)*2+0][0], 0,0,0); \
    acc[(mpv)*2+0][1] = __builtin_amdgcn_mfma_f32_32x32x16_bf16(a[0][1], b[1][1], acc[(mpv)*2+0][1], 0,0,0); \
    acc[(mpv)*2+1][0] = __builtin_amdgcn_mfma_f32_32x32x16_bf16(a[1][1], b[0][1], acc[(mpv)*2+1][0], 0,0,0); \
    acc[(mpv)*2+1][1] = __builtin_amdgcn_mfma_f32_32x32x16_bf16(a[1][1], b[1][1], acc[(mpv)*2+1][1], 0,0,0); } while(0)
#define BAR()  __builtin_amdgcn_s_barrier()
#define LGK0() do { asm volatile("s_waitcnt lgkmcnt(0)" ::: "memory"); \
                    __builtin_amdgcn_sched_barrier(0); } while(0)
#define VM(n)  asm volatile("s_waitcnt vmcnt(" #n ")" ::: "memory")

    // ---- prologue: stage tile 0 into buf 0 (issue order = consume order) ----
    {
        unsigned short* nxt = SMu;
        const int ko = 0;
        STAGE_A(0); STAGE_B(0);
        __builtin_amdgcn_sched_barrier(0);
        STAGE_A(1); STAGE_B(1);
        __builtin_amdgcn_sched_barrier(0);
    }
    VM(4);          // A_k0(0), B_k0(0) landed; k1 halves stay in flight
    BAR();

    s8v a[2][2], b[2][2];
    #pragma unroll 1
    for (int kt = 0; kt < 63; ++kt) {
        const unsigned short* cur = SMu + ((kt & 1) << 15);
        unsigned short* nxt = SMu + (((kt & 1) ^ 1) << 15);
        const int ko = (kt + 1) * BK;
        // phase 0: (kh0, mp0) | stage A_k0(t+1)
        LDB4(0); LDA4(0, 0); STAGE_A(0);
        BAR(); LGK0();
        __builtin_amdgcn_s_setprio(1); MFMA8(0); __builtin_amdgcn_s_setprio(0);
        BAR();
        // phase 1: (kh0, mp1) | stage B_k0(t+1) | vmcnt(4): k1(t) halves landed
        LDA4(0, 1); STAGE_B(0);
        BAR(); LGK0();
        __builtin_amdgcn_s_setprio(1); MFMA8(1); __builtin_amdgcn_s_setprio(0);
        VM(4);
        BAR();
        // phase 2: (kh1, mp0) | stage A_k1(t+1)
        LDB4(1); LDA4(1, 0); STAGE_A(1);
        BAR(); LGK0();
        __builtin_amdgcn_s_setprio(1); MFMA8(0); __builtin_amdgcn_s_setprio(0);
        BAR();
        // phase 3: (kh1, mp1) | stage B_k1(t+1) | vmcnt(4): k0(t+1) halves landed
        LDA4(1, 1); STAGE_B(1);
        BAR(); LGK0();
        __builtin_amdgcn_s_setprio(1); MFMA8(1); __builtin_amdgcn_s_setprio(0);
        VM(4);
        BAR();
    }
    // ---- tail: tile 63, no staging ----
    {
        const unsigned short* cur = SMu + ((63 & 1) << 15);
        LDB4(0); LDA4(0, 0);
        BAR(); LGK0();
        __builtin_amdgcn_s_setprio(1); MFMA8(0); __builtin_amdgcn_s_setprio(0);
        BAR();
        LDA4(0, 1);
        BAR(); LGK0();
        __builtin_amdgcn_s_setprio(1); MFMA8(1); __builtin_amdgcn_s_setprio(0);
        VM(0);
        BAR();
        LDB4(1); LDA4(1, 0);
        BAR(); LGK0();
        __builtin_amdgcn_s_setprio(1); MFMA8(0); __builtin_amdgcn_s_setprio(0);
        BAR();
        LDA4(1, 1);
        BAR(); LGK0();
        __builtin_amdgcn_s_setprio(1); MFMA8(1); __builtin_amdgcn_s_setprio(0);
        BAR();
    }

    // ---- fused epilogue: 4 chunks of 64 m-rows through padded f32 LDS ----
    // 32x32 C/D layout: col = lane&31, row = (reg&3) + 8*(reg>>2) + 4*(lane>>5).
    // All acc indices compile-time (rule #20).
    float* E = (float*)SMu;
    const int EW = 260;
    const int du = lane;
    float bF = bfp[u0 + du], bI = bip[u0 + du], bG = bcp[u0 + du], bO = bop[u0 + du];
    float* outh = out;
    float* outc = out + (size_t)B_DIM * UNITS;
    #pragma unroll
    for (int chk = 0; chk < 4; ++chk) {
        if (wm == (chk >> 1)) {
            #pragma unroll
            for (int mt = 0; mt < 2; ++mt)
                #pragma unroll
                for (int nt = 0; nt < 2; ++nt)
                    #pragma unroll
                    for (int reg = 0; reg < 16; ++reg) {
                        int rl  = mt * 32 + (reg & 3) + 8 * (reg >> 2) + 4 * kg;
                        int col = wn * 64 + nt * 32 + l31;
                        E[rl * EW + col] = acc[(chk & 1) * 2 + mt][nt][reg];
                    }
        }
        __syncthreads();
        #pragma unroll
        for (int v = 0; v < 8; ++v) {
            int rloc = v * 8 + wave;
            float F = E[rloc * EW +       du] + bF;
            float I = E[rloc * EW +  64 + du] + bI;
            float G = E[rloc * EW + 128 + du] + bG;
            float O = E[rloc * EW + 192 + du] + bO;
            int m = m0 + chk * 64 + rloc;
            size_t off = (size_t)m * UNITS + u0 + du;
            float cv = cin[off];
            float fg = 1.f / (1.f + __expf(-F));
            float ig = 1.f / (1.f + __expf(-I));
            float gg = 1.f - 2.f / (1.f + __expf(2.f * G));   // tanh, inf-safe
            float og = 1.f / (1.f + __expf(-O));
            float nc = fg * cv + ig * gg;
            float nh = og * (1.f - 2.f / (1.f + __expf(2.f * nc)));
            outc[off] = nc;
            outh[off] = nh;
        }
        __syncthreads();
    }
}

extern "C" void kernel_launch(void* const* d_in, const int* in_sizes, int n_in,
                              void* d_out, int out_size, void* d_ws, size_t ws_size,
                              hipStream_t stream) {
    const float* x  = (const float*)d_in[0];
    const float* h  = (const float*)d_in[1];
    const float* c  = (const float*)d_in[2];
    const float* Wf = (const float*)d_in[3];
    const float* bf = (const float*)d_in[4];
    const float* Wi = (const float*)d_in[5];
    const float* bi = (const float*)d_in[6];
    const float* Wc = (const float*)d_in[7];
    const float* bc = (const float*)d_in[8];
    const float* Wo = (const float*)d_in[9];
    const float* bo = (const float*)d_in[10];

    unsigned short* zA = (unsigned short*)d_ws;                 // 32 MB
    unsigned short* WB = zA + (size_t)B_DIM * KDIM;             // 64 MB

    hipFuncSetAttribute(reinterpret_cast<const void*>(lstm_gemm),
                        hipFuncAttributeMaxDynamicSharedMemorySize, 131072);

    pack_all<<<NZ_BLOCKS + NW_BLOCKS, 256, 0, stream>>>(x, h, Wf, Wi, Wc, Wo, zA, WB);
    lstm_gemm<<<dim3(512), 512, 131072, stream>>>(
        zA, WB, c, bf, bi, bc, bo, (float*)d_out);
}

// Round 7
// 490.382 us; speedup vs baseline: 1.0570x; 1.0533x over previous
//
#include <hip/hip_runtime.h>
#include <stdint.h>

#define B_DIM 4096
#define DIN   2048
#define UNITS 2048
#define KDIM  4096   // DIN + UNITS
#define BK    64     // k per LDS tile
#define BM    256
#define BN    256    // 4 gates x 64 units

using s8v = __attribute__((ext_vector_type(8))) short;   // 8 x bf16 (4 VGPRs)
using f4v = __attribute__((ext_vector_type(4))) float;   // 4 x f32 acc

__device__ __forceinline__ unsigned short f2bf(float f) {
    union { float f; unsigned u; } v; v.f = f;
    unsigned u = v.u;
    unsigned r = u + 0x7FFFu + ((u >> 16) & 1u);   // RNE
    return (unsigned short)(r >> 16);
}

__device__ __forceinline__ void gl2lds16(const unsigned short* g, unsigned short* l) {
    __builtin_amdgcn_global_load_lds(
        (const __attribute__((address_space(1))) unsigned int*)g,
        (__attribute__((address_space(3))) unsigned int*)l, 16, 0, 0);
}

// ---------------- fused pack: z = [x|h] -> bf16, W -> bf16 transposed ----------------
// blocks [0, 8192): pack_z. blocks [8192, 8192+2048): pack_w (64k x 256n per block).
// T stride 257 (ODD): with an even stride the gather read T[kl+j][ul] has bank =
// f(ul) only (kl*stride vanishes mod 128B) -> 8-way conflict on every scalar read.
// Odd stride adds (kl-dependent)*4 to the bank index -> <=2-way.
#define NZ_BLOCKS 8192
#define NW_BLOCKS 2048
__global__ __launch_bounds__(256) void pack_all(
    const float* __restrict__ x, const float* __restrict__ h,
    const float* __restrict__ Wf, const float* __restrict__ Wi,
    const float* __restrict__ Wc, const float* __restrict__ Wo,
    unsigned short* __restrict__ zA, unsigned short* __restrict__ WB) {
    __shared__ unsigned short T[64][257];
    int t = threadIdx.x;
    int b = blockIdx.x;
    if (b < NZ_BLOCKS) {
        int ch  = b * 256 + t;              // 8-elem chunks, 512/row
        int m   = ch >> 9;
        int pos = (ch & 511) * 8;
        const float* src = (pos < DIN) ? (x + (size_t)m * DIN + pos)
                                       : (h + (size_t)m * UNITS + (pos - DIN));
        float4 v0 = *(const float4*)(src);
        float4 v1 = *(const float4*)(src + 4);
        s8v o;
        o[0]=f2bf(v0.x); o[1]=f2bf(v0.y); o[2]=f2bf(v0.z); o[3]=f2bf(v0.w);
        o[4]=f2bf(v1.x); o[5]=f2bf(v1.y); o[6]=f2bf(v1.z); o[7]=f2bf(v1.w);
        *(s8v*)(zA + (size_t)ch * 8) = o;
        return;
    }
    int bb  = b - NZ_BLOCKS;
    int g   = bb >> 9;            // 512 tiles per gate
    int rem = bb & 511;
    int kt  = rem & 63;           // 64 k-tiles
    int nt  = rem >> 6;           // 8 n-tiles
    const float* Wg = (g == 0) ? Wf : (g == 1) ? Wi : (g == 2) ? Wc : Wo;
    int k0 = kt * 64, n0 = nt * 256;
    const int wv = t >> 6, l = t & 63;
    #pragma unroll
    for (int i = 0; i < 16; ++i) {
        int r = i * 4 + wv;                  // one row per wave per iter
        int c = l * 4;
        float4 v = *(const float4*)(Wg + (size_t)(k0 + r) * UNITS + n0 + c);
        T[r][c+0] = f2bf(v.x); T[r][c+1] = f2bf(v.y);
        T[r][c+2] = f2bf(v.z); T[r][c+3] = f2bf(v.w);
    }
    __syncthreads();
    #pragma unroll
    for (int it = 0; it < 8; ++it) {
        int s  = it * 256 + t;
        int ul = s >> 3;                     // n-row 0..255
        int kl = (s & 7) * 8;                // k chunk
        s8v o;
        #pragma unroll
        for (int j = 0; j < 8; ++j) o[j] = (short)T[kl + j][ul];
        *(s8v*)(WB + (size_t)(g * UNITS + n0 + ul) * KDIM + k0 + kl) = o;
    }
}

// ---------------- 256^2-tile 8-wave phase-pipelined GEMM (16x16x32) + LSTM epilogue ----
// K-loop = round-2 structure (measured: 0 bank conflicts, 264 us, MfmaUtil 47%).
// 32x32 MFMA reverted: its fragment-read pattern pays a structural +4 cyc/b128
// (25.17M conflicts) invariant to swizzle choice (r5 vs r6 identical counters).
// LDS per (buf,kh,matrix) region: 128 lines x 128 B; line L holds rows {2L,2L+1}.
// slog = (row&1)*4 + chunk; physical slot = slog ^ (L&7) -> conflict-free b128 reads.
// Staging dest linear (global_load_lds); inverse swizzle on global source (both-sides).
// XCD mapping kept from r5 (FETCH 312->213 MB proven).
__global__ __launch_bounds__(512, 2) void lstm_gemm(
    const unsigned short* __restrict__ zA,   // 4096 x 4096 bf16
    const unsigned short* __restrict__ WB,   // 8192 x 4096 bf16, row n = g*2048+u
    const float* __restrict__ cin,
    const float* __restrict__ bfp, const float* __restrict__ bip,
    const float* __restrict__ bcp, const float* __restrict__ bop,
    float* __restrict__ out) {
    extern __shared__ unsigned short SMu[];   // 131072 B

    const int t    = threadIdx.x;
    const int lane = t & 63;
    const int wave = t >> 6;       // 0..7
    const int wm   = wave >> 2;    // 0..1  (m half)
    const int wn   = wave & 3;     // 0..3  (gate)
    const int fr   = lane & 15;
    const int q    = lane >> 4;

    // XCD-aware mapping: 2x4 super-grid of XCDs, each XCD owns 8 m-tiles x 8 u-tiles
    int bid = blockIdx.x;
    int xcd = bid & 7, loc = bid >> 3;
    const int m0 = (((xcd & 1) << 3) | (loc & 7)) * BM;    // 16 m-tiles
    const int u0 = (((xcd >> 1) << 3) | (loc >> 3)) * 64;  // 32 u-tiles

    // ---- staging: slots s = t and t+512 per region; slot -> (line, phys slot) ----
    const int L    = t >> 3;
    const int p    = t & 7;
    const int slog = p ^ (L & 7);
    const int rr   = 2 * L + (slog >> 2);    // row 0..127
    const int ch   = slog & 3;               // 8-bf16 chunk within kh-half
    const unsigned short* gA0 = zA + (size_t)(m0 + rr) * KDIM + ch * 8;
    const unsigned short* gB0 = WB + (size_t)((rr >> 6) * UNITS + u0 + (rr & 63)) * KDIM + ch * 8;
    const int dst0 = t * 8;                  // ushort offsets, linear
    const int dst1 = (t + 512) * 8;

    // ---- fragment read offsets (ushorts) ----
    // row r = base16 + fr (base16 mult of 16): line = base/2 + fh, fh = fr>>1,
    // phys slot = ((fr&1)*4 + q) ^ (fh)  (line&7 == fh for 16-row-aligned bases).
    const int fh      = fr >> 1;
    const int laneoff = fh * 64 + ((((fr & 1) << 2) | q) ^ fh) * 8;
    const int aoff = wm * 4096 + laneoff;            // + (mq*4+ii)*512 + kh*8192 (+buf)
    const int boff = 16384 + wn * 2048 + laneoff;    // + jj*512       + kh*8192 (+buf)

    f4v acc[8][4];
    #pragma unroll
    for (int i = 0; i < 8; ++i)
        #pragma unroll
        for (int j = 0; j < 4; ++j) acc[i][j] = (f4v){0.f, 0.f, 0.f, 0.f};

#define STAGE_A(khv) do { \
    gl2lds16(gA0 + ko + (khv)*32, nxt + (khv)*8192 + dst0); \
    gl2lds16(gA0 + (size_t)128*KDIM + ko + (khv)*32, nxt + (khv)*8192 + dst1); } while(0)
#define STAGE_B(khv) do { \
    gl2lds16(gB0 + ko + (khv)*32, nxt + 16384 + (khv)*8192 + dst0); \
    gl2lds16(gB0 + (size_t)2*UNITS*KDIM + ko + (khv)*32, nxt + 16384 + (khv)*8192 + dst1); } while(0)
#define LDB4(khv) { _Pragma("unroll") for (int jj = 0; jj < 4; ++jj) \
    b[jj] = *(const s8v*)(cur + boff + (khv)*8192 + jj*512); }
#define LDA4(khv, mqv) { _Pragma("unroll") for (int ii = 0; ii < 4; ++ii) \
    a[ii] = *(const s8v*)(cur + aoff + (khv)*8192 + ((mqv)*4+ii)*512); }
#define MFMA16(mqv) { _Pragma("unroll") for (int ii = 0; ii < 4; ++ii) \
    _Pragma("unroll") for (int jj = 0; jj < 4; ++jj) \
    acc[(mqv)*4+ii][jj] = __builtin_amdgcn_mfma_f32_16x16x32_bf16(a[ii], b[jj], acc[(mqv)*4+ii][jj], 0, 0, 0); }
#define BAR()  __builtin_amdgcn_s_barrier()
#define LGK0() do { asm volatile("s_waitcnt lgkmcnt(0)" ::: "memory"); \
                    __builtin_amdgcn_sched_barrier(0); } while(0)
#define VM(n)  asm volatile("s_waitcnt vmcnt(" #n ")" ::: "memory")

    // ---- prologue: stage tile 0 into buf 0 (issue order = consume order) ----
    {
        unsigned short* nxt = SMu;
        const int ko = 0;
        STAGE_A(0); STAGE_B(0);
        __builtin_amdgcn_sched_barrier(0);
        STAGE_A(1); STAGE_B(1);
        __builtin_amdgcn_sched_barrier(0);
    }
    VM(4);          // A_k0(0), B_k0(0) landed; k1 halves stay in flight
    BAR();

    s8v a[4], b[4];
    #pragma unroll 1
    for (int kt = 0; kt < 63; ++kt) {
        const unsigned short* cur = SMu + ((kt & 1) << 15);
        unsigned short* nxt = SMu + (((kt & 1) ^ 1) << 15);
        const int ko = (kt + 1) * BK;
        // phase 0: (kh0, mq0) | stage A_k0(t+1)
        LDB4(0); LDA4(0, 0); STAGE_A(0);
        BAR(); LGK0();
        __builtin_amdgcn_s_setprio(1); MFMA16(0); __builtin_amdgcn_s_setprio(0);
        BAR();
        // phase 1: (kh0, mq1) | stage B_k0(t+1) | vmcnt(4): k1(t) halves landed
        LDA4(0, 1); STAGE_B(0);
        BAR(); LGK0();
        __builtin_amdgcn_s_setprio(1); MFMA16(1); __builtin_amdgcn_s_setprio(0);
        VM(4);
        BAR();
        // phase 2: (kh1, mq0) | stage A_k1(t+1)
        LDB4(1); LDA4(1, 0); STAGE_A(1);
        BAR(); LGK0();
        __builtin_amdgcn_s_setprio(1); MFMA16(0); __builtin_amdgcn_s_setprio(0);
        BAR();
        // phase 3: (kh1, mq1) | stage B_k1(t+1) | vmcnt(4): k0(t+1) halves landed
        LDA4(1, 1); STAGE_B(1);
        BAR(); LGK0();
        __builtin_amdgcn_s_setprio(1); MFMA16(1); __builtin_amdgcn_s_setprio(0);
        VM(4);
        BAR();
    }
    // ---- tail: tile 63, no staging ----
    {
        const unsigned short* cur = SMu + ((63 & 1) << 15);
        LDB4(0); LDA4(0, 0);
        BAR(); LGK0();
        __builtin_amdgcn_s_setprio(1); MFMA16(0); __builtin_amdgcn_s_setprio(0);
        BAR();
        LDA4(0, 1);
        BAR(); LGK0();
        __builtin_amdgcn_s_setprio(1); MFMA16(1); __builtin_amdgcn_s_setprio(0);
        VM(0);
        BAR();
        LDB4(1); LDA4(1, 0);
        BAR(); LGK0();
        __builtin_amdgcn_s_setprio(1); MFMA16(0); __builtin_amdgcn_s_setprio(0);
        BAR();
        LDA4(1, 1);
        BAR(); LGK0();
        __builtin_amdgcn_s_setprio(1); MFMA16(1); __builtin_amdgcn_s_setprio(0);
        BAR();
    }

    // ---- fused epilogue: 4 chunks of 64 m-rows through padded f32 LDS ----
    // chk loop FULLY unrolled: all acc indices compile-time (rule #20).
    float* E = (float*)SMu;
    const int EW = 260;
    const int du = lane;
    float bF = bfp[u0 + du], bI = bip[u0 + du], bG = bcp[u0 + du], bO = bop[u0 + du];
    float* outh = out;
    float* outc = out + (size_t)B_DIM * UNITS;
    #pragma unroll
    for (int chk = 0; chk < 4; ++chk) {
        if (wm == (chk >> 1)) {
            const int i0 = (chk & 1) * 4;
            #pragma unroll
            for (int ii = 0; ii < 4; ++ii)
                #pragma unroll
                for (int j = 0; j < 4; ++j) {
                    int col = wn * 64 + j * 16 + fr;
                    #pragma unroll
                    for (int pp = 0; pp < 4; ++pp)
                        E[(ii * 16 + q * 4 + pp) * EW + col] = acc[i0 + ii][j][pp];
                }
        }
        __syncthreads();
        #pragma unroll
        for (int v = 0; v < 8; ++v) {
            int rloc = v * 8 + wave;
            float F = E[rloc * EW +       du] + bF;
            float I = E[rloc * EW +  64 + du] + bI;
            float G = E[rloc * EW + 128 + du] + bG;
            float O = E[rloc * EW + 192 + du] + bO;
            int m = m0 + chk * 64 + rloc;
            size_t off = (size_t)m * UNITS + u0 + du;
            float cv = cin[off];
            float fg = 1.f / (1.f + __expf(-F));
            float ig = 1.f / (1.f + __expf(-I));
            float gg = 1.f - 2.f / (1.f + __expf(2.f * G));   // tanh, inf-safe
            float og = 1.f / (1.f + __expf(-O));
            float nc = fg * cv + ig * gg;
            float nh = og * (1.f - 2.f / (1.f + __expf(2.f * nc)));
            outc[off] = nc;
            outh[off] = nh;
        }
        __syncthreads();
    }
}

extern "C" void kernel_launch(void* const* d_in, const int* in_sizes, int n_in,
                              void* d_out, int out_size, void* d_ws, size_t ws_size,
                              hipStream_t stream) {
    const float* x  = (const float*)d_in[0];
    const float* h  = (const float*)d_in[1];
    const float* c  = (const float*)d_in[2];
    const float* Wf = (const float*)d_in[3];
    const float* bf = (const float*)d_in[4];
    const float* Wi = (const float*)d_in[5];
    const float* bi = (const float*)d_in[6];
    const float* Wc = (const float*)d_in[7];
    const float* bc = (const float*)d_in[8];
    const float* Wo = (const float*)d_in[9];
    const float* bo = (const float*)d_in[10];

    unsigned short* zA = (unsigned short*)d_ws;                 // 32 MB
    unsigned short* WB = zA + (size_t)B_DIM * KDIM;             // 64 MB

    hipFuncSetAttribute(reinterpret_cast<const void*>(lstm_gemm),
                        hipFuncAttributeMaxDynamicSharedMemorySize, 131072);

    pack_all<<<NZ_BLOCKS + NW_BLOCKS, 256, 0, stream>>>(x, h, Wf, Wi, Wc, Wo, zA, WB);
    lstm_gemm<<<dim3(512), 512, 131072, stream>>>(
        zA, WB, c, bf, bi, bc, bo, (float*)d_out);
}